// Round 14
// baseline (30.031 us; speedup 1.0000x reference)
//
#include <hip/hip_runtime.h>

// Degrade: per-sample depthwise 13x13 cross-correlation, stride 4,
// replicate padding p=6.  im: [8,4,1024,1024] f32, kernel: [8,1,13,13] f32,
// out: [8,4,256,256] f32.
//
// R13 = R12 (29.7us: full-depth pinned load burst) with a ROLLING window
// to trade 6 registers of depth for +33% occupancy:
//   load ph0,ph1,ph2 (19) | SB | fma ph0 | SB | load ph3 (6) | SB | fma 1,2,3
// Peak live x regs 25 -> 19 (~110 VGPR total), __launch_bounds__(256,4)
// -> 4 waves/SIMD resident (was 3).  Outstanding loads/wave stays 18-19.
// Theory: residual bind is per-CU outstanding-request capacity; total
// outstanding scales with resident waves.

#define KS 13
#define IH 1024
#define IW 1024
#define OH 256
#define OW 256
#define WOX 61              // valid outputs per wave in x (3-lane halo)
#define TH 4                // output rows per thread
#define NROWS (4 * TH + 9)  // 25 input rows per thread
#define GRIDX 5
#define GRIDY 16
#define GRIDZ 32
#define NWG (GRIDX * GRIDY * GRIDZ)     // 2560, divisible by 8 XCDs
#define PERX (NWG / 8)                  // 320 blocks per XCD chunk

__device__ __forceinline__ float pick_c(const float4& x, int s) {
    float a = (s & 2) ? x.z : x.x;
    float b = (s & 2) ? x.w : x.y;
    return (s & 1) ? b : a;
}

// ---- issue loads for ky-phase R (rows t = R + 4u, u < N) ----
template <int R, int N, bool EDGE>
__device__ __forceinline__ void load_phase(
    float4 (&x)[N], const float* __restrict__ pl,
    int gy0, int fbase, int cb)
{
#pragma unroll
    for (int u = 0; u < N; ++u) {
        const int t = R + 4 * u;                   // compile-time
        const int gy = min(max(gy0 + t, 0), IH - 1);   // scalar
        x[u] = *(const float4*)(pl + (size_t)gy * IW + (EDGE ? cb : fbase));
    }
}

// ---- consume ky-phase R ----
template <int R, int N, bool EDGE>
__device__ __forceinline__ void fma_phase(
    const float4 (&x)[N], const float* __restrict__ kb, float acc[TH][4],
    bool interior, int s0, int s1, int s2, int s3)
{
#pragma unroll
    for (int u = 0; u < N; ++u) {
        const int t = R + 4 * u;                   // compile-time
        float4 v = x[u];
        if (EDGE && !interior) {                   // border lanes only
            float4 f;
            f.x = pick_c(v, s0); f.y = pick_c(v, s1);
            f.z = pick_c(v, s2); f.w = pick_c(v, s3);
            v = f;
        }
#pragma unroll
        for (int ky = R; ky < KS; ky += 4) {
            const int j = (t - ky) >> 2;           // compile-time
            if (j >= 0 && j < TH) {
                const float* __restrict__ kr = kb + ky * KS;
                // chunk float c -> tap kx=4p+c-2 of output (lane-p)
                acc[j][0] = fmaf(v.z, kr[0],  acc[j][0]);
                acc[j][0] = fmaf(v.w, kr[1],  acc[j][0]);
                acc[j][1] = fmaf(v.x, kr[2],  acc[j][1]);
                acc[j][1] = fmaf(v.y, kr[3],  acc[j][1]);
                acc[j][1] = fmaf(v.z, kr[4],  acc[j][1]);
                acc[j][1] = fmaf(v.w, kr[5],  acc[j][1]);
                acc[j][2] = fmaf(v.x, kr[6],  acc[j][2]);
                acc[j][2] = fmaf(v.y, kr[7],  acc[j][2]);
                acc[j][2] = fmaf(v.z, kr[8],  acc[j][2]);
                acc[j][2] = fmaf(v.w, kr[9],  acc[j][2]);
                acc[j][3] = fmaf(v.x, kr[10], acc[j][3]);
                acc[j][3] = fmaf(v.y, kr[11], acc[j][3]);
                acc[j][3] = fmaf(v.z, kr[12], acc[j][3]);
            }
        }
    }
}

template <bool EDGE>
__device__ __forceinline__ void conv_body(
    const float* __restrict__ pl, const float* __restrict__ kb,
    int gy0, int fbase, int cb, int s0, int s1, int s2, int s3,
    bool interior, float acc[TH][4])
{
    // phase row counts: r=0 -> 7 (t=0..24); r=1,2,3 -> 6
    float4 x0[7], x1[6], x2[6], x3[6];

    load_phase<0, 7, EDGE>(x0, pl, gy0, fbase, cb);
    load_phase<1, 6, EDGE>(x1, pl, gy0, fbase, cb);
    load_phase<2, 6, EDGE>(x2, pl, gy0, fbase, cb);   // 19 in flight
    __builtin_amdgcn_sched_barrier(0);

    fma_phase<0, 7, EDGE>(x0, kb, acc, interior, s0, s1, s2, s3);
    __builtin_amdgcn_sched_barrier(0);

    load_phase<3, 6, EDGE>(x3, pl, gy0, fbase, cb);   // refill to 18
    __builtin_amdgcn_sched_barrier(0);

    fma_phase<1, 6, EDGE>(x1, kb, acc, interior, s0, s1, s2, s3);
    fma_phase<2, 6, EDGE>(x2, kb, acc, interior, s0, s1, s2, s3);
    fma_phase<3, 6, EDGE>(x3, kb, acc, interior, s0, s1, s2, s3);
}

__global__ __launch_bounds__(256, 4) void degrade_kernel(
    const float* __restrict__ im,
    const float* __restrict__ kern,
    float* __restrict__ out)
{
    // ---- XCD-aware decode: y-adjacent blocks + whole planes per XCD ----
    const int h   = blockIdx.x;                    // round-robins XCDs
    const int lid = (h & 7) * PERX + (h >> 3);     // bijective remap
    const int by  = lid & 15;                      // y fastest
    const int tXZ = lid >> 4;
    const int bx  = tXZ % GRIDX;
    const int bz  = tXZ / GRIDX;

    const int plane = bz;                  // b*4 + c
    const int b     = plane >> 2;
    const int tid   = threadIdx.x;
    const int lane  = tid & 63;
    const int w     = __builtin_amdgcn_readfirstlane(tid >> 6);
    const int ox0   = bx * WOX;
    const int oy0   = by * (4 * TH) + w * TH;      // scalar

    const float* __restrict__ pl = im + (size_t)plane * (IH * IW);
    const float* __restrict__ kb = kern + b * (KS * KS);   // wave-uniform

    // this lane's 16B chunk: floats fbase..fbase+3 of each input row
    const int fbase = 4 * ox0 - 8 + 4 * lane;
    const int cb    = min(max(fbase, 0), IW - 4);
    const bool interior = (fbase == cb);
    const int s0 = min(max(fbase + 0, 0), IW - 1) - cb;
    const int s1 = min(max(fbase + 1, 0), IW - 1) - cb;
    const int s2 = min(max(fbase + 2, 0), IW - 1) - cb;
    const int s3 = min(max(fbase + 3, 0), IW - 1) - cb;

    const int gy0 = 4 * oy0 - 6;           // scalar

    float acc[TH][4];
#pragma unroll
    for (int j = 0; j < TH; ++j)
#pragma unroll
        for (int p = 0; p < 4; ++p) acc[j][p] = 0.0f;

    // blocks bx=1..3 are provably interior (fbase in [236,979])
    if (bx == 0 || bx == GRIDX - 1)
        conv_body<true >(pl, kb, gy0, fbase, cb, s0, s1, s2, s3, interior, acc);
    else
        conv_body<false>(pl, kb, gy0, fbase, cb, s0, s1, s2, s3, interior, acc);

    // combine partials across lanes (once) and store
    const bool valid = (lane < WOX) && (ox0 + lane < OW);
#pragma unroll
    for (int j = 0; j < TH; ++j) {
        float v = acc[j][0]
                + __shfl(acc[j][1], lane + 1, 64)
                + __shfl(acc[j][2], lane + 2, 64)
                + __shfl(acc[j][3], lane + 3, 64);
        if (valid)
            out[((size_t)plane * OH + oy0 + j) * OW + ox0 + lane] = v;
    }
}

extern "C" void kernel_launch(void* const* d_in, const int* in_sizes, int n_in,
                              void* d_out, int out_size, void* d_ws, size_t ws_size,
                              hipStream_t stream)
{
    const float* im   = (const float*)d_in[0];
    const float* kern = (const float*)d_in[1];
    float* out        = (float*)d_out;

    degrade_kernel<<<dim3(NWG, 1, 1), 256, 0, stream>>>(im, kern, out);
}